// Round 1
// baseline (42908.224 us; speedup 1.0000x reference)
//
#include <hip/hip_runtime.h>

// ---------------------------------------------------------------------------
// LSTM (B=128, T=512, D=512, H=1024, O=256), forget bias 1.0
// Plan:
//   prep:    f16 conversions/transposes/fragment-packing of weights
//   phase1:  xw = X @ W_x + b  (f16 MFMA GEMM, 65536x512x4096) -> ws
//   phase2:  persistent cooperative kernel, 512 sequential steps.
//            8 teams x 16 batch rows; 32 blocks/team each owning 32 hidden
//            units (128 gate cols). W_h fragments live in VGPRs. h exchanged
//            through global double buffer + per-step flags (agent scope).
//   phase3:  logits = lstm_out @ W_out + b_out (f16 MFMA GEMM)
// ---------------------------------------------------------------------------

typedef _Float16 f16;
typedef _Float16 half8 __attribute__((ext_vector_type(8)));
typedef float floatx4 __attribute__((ext_vector_type(4)));

#define AS1 __attribute__((address_space(1)))
#define AS3 __attribute__((address_space(3)))

__device__ __forceinline__ void gload_lds16(const void* g, void* l) {
  __builtin_amdgcn_global_load_lds((const AS1 void*)g, (AS3 void*)l, 16, 0, 0);
}

__device__ __forceinline__ float sigm(float x) { return 1.f / (1.f + __expf(-x)); }
__device__ __forceinline__ float tanh_fast(float x) {
  float ax = fabsf(x);
  float e = __expf(2.f * ax);          // overflows to +inf for big |x| -> t=1 exactly
  float t = 1.f - 2.f / (e + 1.f);
  return copysignf(t, x);
}

// ---------------- workspace layout ----------------
static constexpr size_t XW_OFF  = 0;
static constexpr size_t XW_BY   = (size_t)65536 * 4096 * 2;        // 536870912
static constexpr size_t L16_OFF = XW_OFF + XW_BY;                  // lstm_out f16 (aliases in16)
static constexpr size_t L16_BY  = (size_t)65536 * 1024 * 2;        // 134217728
static constexpr size_t IN16_OFF = L16_OFF;                        // inputs f16 (phase1 only)
static constexpr size_t WXT_OFF = L16_OFF + L16_BY;
static constexpr size_t WXT_BY  = (size_t)4096 * 512 * 2;
static constexpr size_t WOT_OFF = WXT_OFF + WXT_BY;
static constexpr size_t WOT_BY  = (size_t)256 * 1024 * 2;
static constexpr size_t WPK_OFF = WOT_OFF + WOT_BY;
static constexpr size_t WPK_BY  = (size_t)524288 * 8 * 2;          // W_h frag-packed
static constexpr size_t TH_OFF  = WPK_OFF + WPK_BY;
static constexpr size_t TH_BY   = (size_t)2 * 128 * 1024 * 2;      // h ping-pong
static constexpr size_t FLG_OFF = TH_OFF + TH_BY;
static constexpr size_t FLG_BY  = (size_t)8 * 512 * 4;             // flags[team][t]
static constexpr size_t WS_NEED = FLG_OFF + FLG_BY;

// ---------------- prep kernels ----------------
__global__ __launch_bounds__(256) void conv_f32_to_f16(const float* __restrict__ in,
                                                       f16* __restrict__ out) {
  size_t i = (size_t)blockIdx.x * 256 + threadIdx.x;
  const float4* in4 = (const float4*)in;
  float4 a = in4[i * 2], b = in4[i * 2 + 1];
  half8 v = {(f16)a.x, (f16)a.y, (f16)a.z, (f16)a.w,
             (f16)b.x, (f16)b.y, (f16)b.z, (f16)b.w};
  *(half8*)(out + i * 8) = v;
}

// out[c][r] = (f16)in[r][c]; grid = (C/64, R/64)
__global__ __launch_bounds__(256) void transpose_f32_to_f16(const float* __restrict__ in,
                                                            f16* __restrict__ out,
                                                            int R, int C) {
  __shared__ float tile[64][65];
  int tx = threadIdx.x & 63, ty = threadIdx.x >> 6;
  int c0 = blockIdx.x * 64, r0 = blockIdx.y * 64;
#pragma unroll
  for (int q = 0; q < 16; ++q) {
    int r = q * 4 + ty;
    tile[r][tx] = in[(size_t)(r0 + r) * C + c0 + tx];
  }
  __syncthreads();
#pragma unroll
  for (int q = 0; q < 16; ++q) {
    int oc = q * 4 + ty;
    out[(size_t)(c0 + oc) * R + r0 + tx] = (f16)tile[tx][oc];
  }
}

// Pack W_h (rows 512..1535 of W_lstm) into per-(colblock,wave,ni,ks,lane) f16x8
// fragments matching the phase-2 MFMA B-operand layout (n=lane&15, k=(lane>>4)*8+e).
__global__ __launch_bounds__(256) void pack_wh(const float* __restrict__ W,
                                               f16* __restrict__ wpack) {
  int s = blockIdx.x * 256 + threadIdx.x;   // 0 .. 524287
  int lane = s & 63;
  int ks = (s >> 6) & 7;
  int ni = (s >> 9) & 3;
  int w  = (s >> 11) & 7;
  int cb = s >> 14;                          // 0..31
  int nh = w & 1, ksl = w >> 1;
  int c = nh * 64 + ni * 16 + (lane & 15);   // block-local col 0..127
  int g = c >> 5, ul = c & 31;
  int ncol = g * 1024 + cb * 32 + ul;        // global gate col
  int kb = ksl * 256 + ks * 32 + (lane >> 4) * 8;
  half8 v;
#pragma unroll
  for (int e = 0; e < 8; ++e)
    v[e] = (f16)W[(size_t)(512 + kb + e) * 4096 + ncol];
  ((half8*)wpack)[s] = v;
}

// ---------------- generic f16 MFMA GEMM: C = A[MxK] * Bt[NxK]^T + bias ----------------
template <typename OT>
__global__ __launch_bounds__(256) void gemm_f16(const f16* __restrict__ A,
                                                const f16* __restrict__ Bt,
                                                const float* __restrict__ bias,
                                                OT* __restrict__ C,
                                                int M, int N, int K) {
  __shared__ __align__(16) char smem[32768];   // As 16K | Bs 16K
  const int tid = threadIdx.x;
  const int n0 = blockIdx.x * 128, m0 = blockIdx.y * 128;
  const int l = tid & 63, w = tid >> 6;
  const int wr = w >> 1, wc = w & 1;
  const int r16 = l & 15, hi = l >> 4;
  floatx4 acc[4][4];
#pragma unroll
  for (int a = 0; a < 4; ++a)
#pragma unroll
    for (int b = 0; b < 4; ++b) acc[a][b] = (floatx4){0.f, 0.f, 0.f, 0.f};

  const int nk = K >> 6;
  for (int kk = 0; kk < nk; ++kk) {
    __syncthreads();
#pragma unroll
    for (int q = 0; q < 4; ++q) {
      int c = q * 256 + tid;
      int row = c >> 3, g8 = c & 7;
      gload_lds16(A + (size_t)(m0 + row) * K + kk * 64 + g8 * 8, smem + c * 16);
    }
#pragma unroll
    for (int q = 0; q < 4; ++q) {
      int c = q * 256 + tid;
      int row = c >> 3, g8 = c & 7;
      gload_lds16(Bt + (size_t)(n0 + row) * K + kk * 64 + g8 * 8, smem + 16384 + c * 16);
    }
    __syncthreads();
#pragma unroll
    for (int ks = 0; ks < 2; ++ks) {
      half8 af[4], bf[4];
#pragma unroll
      for (int mi = 0; mi < 4; ++mi)
        af[mi] = *(const half8*)(smem + ((wr * 64 + mi * 16 + r16) * 64 + ks * 32 + hi * 8) * 2);
#pragma unroll
      for (int ni = 0; ni < 4; ++ni)
        bf[ni] = *(const half8*)(smem + 16384 +
                                 ((wc * 64 + ni * 16 + r16) * 64 + ks * 32 + hi * 8) * 2);
#pragma unroll
      for (int mi = 0; mi < 4; ++mi)
#pragma unroll
        for (int ni = 0; ni < 4; ++ni)
          acc[mi][ni] = __builtin_amdgcn_mfma_f32_16x16x32_f16(af[mi], bf[ni], acc[mi][ni], 0, 0, 0);
    }
  }
#pragma unroll
  for (int ni = 0; ni < 4; ++ni) {
    int col = n0 + wc * 64 + ni * 16 + r16;
    float bv = bias[col];
#pragma unroll
    for (int mi = 0; mi < 4; ++mi)
#pragma unroll
      for (int rr = 0; rr < 4; ++rr) {
        int row = m0 + wr * 64 + mi * 16 + hi * 4 + rr;
        C[(size_t)row * N + col] = (OT)(acc[mi][ni][rr] + bv);
      }
  }
}

// ---------------- phase 2: persistent recurrent kernel ----------------
// grid 256 blocks x 512 threads. block bk: team = bk>>5 (16 batch rows),
// colblock cb = bk&31 (hidden units u0..u0+31 -> gate cols {g*1024+u0+ul}).
// wave w: ksl = w>>1 (K slice of 256), nh = w&1 (64-col half).
__global__ __launch_bounds__(512, 2)
void lstm_phase2(const f16* __restrict__ wpack, const f16* __restrict__ xw,
                 const float* __restrict__ c_in, const float* __restrict__ h_in,
                 const int* __restrict__ seq_lens,
                 f16* teamh, int* flags,
                 float* __restrict__ lstm_out, f16* __restrict__ lstm16,
                 float* __restrict__ c_out, float* __restrict__ h_out) {
  __shared__ __align__(16) char smem[65536];   // h_lds 32K (swizzled) | red 32K
  const int tid = threadIdx.x;
  const int bk = blockIdx.x;
  const int team = bk >> 5, cb = bk & 31;
  const int b0 = team * 16;
  const int u0 = cb * 32;
  const int l = tid & 63, w = tid >> 6;
  const int nh = w & 1, ksl = w >> 1;
  const int r16 = l & 15, hi = l >> 4;

  // persistent W_h fragments: 32 x f16x8 = 128 VGPRs
  half8 wf[4][8];
  {
    const half8* wp = (const half8*)wpack;
    size_t base = (size_t)((cb * 8 + w) * 4) * 8 * 64;
#pragma unroll
    for (int ni = 0; ni < 4; ++ni)
#pragma unroll
      for (int ks = 0; ks < 8; ++ks)
        wf[ni][ks] = wp[base + (size_t)(ni * 8 + ks) * 64 + l];
  }

  const int bb = tid >> 5, ul = tid & 31;     // consumer identity: batch row, unit
  const int bglob = b0 + bb;
  const int nunit = u0 + ul;
  float creg = c_in[bglob * 1024 + nunit];
  float hreg = h_in[bglob * 1024 + nunit];
  const int slen = seq_lens[bglob];

  float* red = (float*)(smem + 32768);
  int* myflags = flags + team * 512;

#pragma unroll 1
  for (int t = 0; t < 512; ++t) {
    // prefetch this step's x-projection (independent of the flag)
    f16 xwv0, xwv1, xwv2, xwv3;
    {
      const f16* xp = xw + ((size_t)bglob * 512 + t) * 4096 + nunit;
      xwv0 = xp[0]; xwv1 = xp[1024]; xwv2 = xp[2048]; xwv3 = xp[3072];
    }

    if (t > 0) {
      if (tid == 0) {
        while (__hip_atomic_load(myflags + (t - 1), __ATOMIC_ACQUIRE,
                                 __HIP_MEMORY_SCOPE_AGENT) < 32)
          __builtin_amdgcn_s_sleep(1);
      }
      __syncthreads();
      __threadfence();   // acquire: invalidate stale cross-XCD lines
      const char* hb = (const char*)teamh + (size_t)(t & 1) * (128 * 1024 * 2);
#pragma unroll
      for (int q = 0; q < 4; ++q) {
        int G = q * 512 + tid;          // 16B granule id; 128 granules per h row
        int r = G >> 7, p = G & 127;
        int dg = p ^ (r & 7);           // inverse-swizzled source (linear LDS dest)
        gload_lds16(hb + ((size_t)(b0 + r) * 1024 + dg * 8) * 2, smem + G * 16);
      }
    } else {
      // first step: stage h_in (fp32 -> f16) with the same swizzle
#pragma unroll
      for (int q = 0; q < 4; ++q) {
        int G = q * 512 + tid;
        int r = G >> 7, p = G & 127;
        int dg = p ^ (r & 7);
        const float* s = h_in + (size_t)(b0 + r) * 1024 + dg * 8;
        half8 v;
#pragma unroll
        for (int e = 0; e < 8; ++e) v[e] = (f16)s[e];
        *(half8*)(smem + G * 16) = v;
      }
    }
    __syncthreads();

    // MFMA: gates_partial[16 x 64cols] over K slice of 256
    floatx4 acc0 = {0.f, 0.f, 0.f, 0.f}, acc1 = acc0, acc2 = acc0, acc3 = acc0;
#pragma unroll
    for (int ks = 0; ks < 8; ++ks) {
      int gran = ksl * 32 + ks * 4 + hi;
      int phys = gran ^ (r16 & 7);      // swizzled read -> conflict-free b128
      half8 a = *(const half8*)(smem + r16 * 2048 + phys * 16);
      acc0 = __builtin_amdgcn_mfma_f32_16x16x32_f16(a, wf[0][ks], acc0, 0, 0, 0);
      acc1 = __builtin_amdgcn_mfma_f32_16x16x32_f16(a, wf[1][ks], acc1, 0, 0, 0);
      acc2 = __builtin_amdgcn_mfma_f32_16x16x32_f16(a, wf[2][ks], acc2, 0, 0, 0);
      acc3 = __builtin_amdgcn_mfma_f32_16x16x32_f16(a, wf[3][ks], acc3, 0, 0, 0);
    }
    {
      int cbase = nh * 64 + r16;
      int rbase = ksl * 16 + hi * 4;
#pragma unroll
      for (int rr = 0; rr < 4; ++rr) {
        float* rp = red + (size_t)(rbase + rr) * 128 + cbase;
        rp[0] = acc0[rr]; rp[16] = acc1[rr]; rp[32] = acc2[rr]; rp[48] = acc3[rr];
      }
    }
    __syncthreads();

    // reduce 4 K-slices + x-projection, then gate nonlinearities
    float g0 = (float)xwv0, g1 = (float)xwv1, g2 = (float)xwv2, g3 = (float)xwv3;
#pragma unroll
    for (int p = 0; p < 4; ++p) {
      const float* rp = red + ((size_t)p * 16 + bb) * 128 + ul;
      g0 += rp[0]; g1 += rp[32]; g2 += rp[64]; g3 += rp[96];
    }
    float nc = creg * sigm(g2 + 1.f) + sigm(g0) * tanh_fast(g1);   // i,j,f,o order
    float nhv = tanh_fast(nc) * sigm(g3);
    bool valid = t < slen;
    if (valid) { creg = nc; hreg = nhv; }
    float outv = valid ? nhv : 0.f;
    size_t orow = ((size_t)bglob * 512 + t) * 1024 + nunit;
    lstm_out[orow] = outv;
    lstm16[orow] = (f16)outv;
    teamh[(size_t)((t + 1) & 1) * 131072 + bglob * 1024 + nunit] = (f16)hreg;

    __threadfence();          // release h stores to agent scope
    __syncthreads();
    if (tid == 0)
      __hip_atomic_fetch_add(myflags + t, 1, __ATOMIC_RELEASE, __HIP_MEMORY_SCOPE_AGENT);
  }

  c_out[bglob * 1024 + nunit] = creg;
  h_out[bglob * 1024 + nunit] = hreg;
}

// ---------------- host ----------------
extern "C" void kernel_launch(void* const* d_in, const int* in_sizes, int n_in,
                              void* d_out, int out_size, void* d_ws, size_t ws_size,
                              hipStream_t stream) {
  const float* inputs  = (const float*)d_in[0];
  const float* c_in    = (const float*)d_in[1];
  const float* h_in    = (const float*)d_in[2];
  const float* W_lstm  = (const float*)d_in[3];
  const float* b_lstm  = (const float*)d_in[4];
  const float* W_out   = (const float*)d_in[5];
  const float* b_out   = (const float*)d_in[6];
  const int*   seq_lens= (const int*)d_in[7];

  float* logits  = (float*)d_out;
  float* lstm_out= logits + (size_t)65536 * 256;
  float* c_out   = lstm_out + (size_t)65536 * 1024;
  float* h_out   = c_out + (size_t)128 * 1024;

  if (ws_size < WS_NEED) return;   // fail visibly (poison stays) rather than corrupt

  char* ws = (char*)d_ws;
  f16* xw    = (f16*)(ws + XW_OFF);
  f16* in16  = (f16*)(ws + IN16_OFF);
  f16* l16   = (f16*)(ws + L16_OFF);
  f16* wxt   = (f16*)(ws + WXT_OFF);
  f16* wot   = (f16*)(ws + WOT_OFF);
  f16* wpk   = (f16*)(ws + WPK_OFF);
  f16* teamh = (f16*)(ws + TH_OFF);
  int* flags = (int*)(ws + FLG_OFF);

  hipMemsetAsync(flags, 0, FLG_BY, stream);
  conv_f32_to_f16<<<16384, 256, 0, stream>>>(inputs, in16);
  transpose_f32_to_f16<<<dim3(64, 8), 256, 0, stream>>>(W_lstm, wxt, 512, 4096);
  transpose_f32_to_f16<<<dim3(4, 16), 256, 0, stream>>>(W_out, wot, 1024, 256);
  pack_wh<<<2048, 256, 0, stream>>>(W_lstm, wpk);

  // phase 1: xw = X @ W_x + b_lstm
  gemm_f16<f16><<<dim3(32, 512), 256, 0, stream>>>(in16, wxt, b_lstm, xw, 65536, 4096, 512);

  // phase 2: persistent recurrence (cooperative => co-residency guaranteed)
  {
    const f16* wpk_c = wpk;
    const f16* xw_c  = xw;
    void* args[] = {(void*)&wpk_c, (void*)&xw_c, (void*)&c_in, (void*)&h_in,
                    (void*)&seq_lens, (void*)&teamh, (void*)&flags,
                    (void*)&lstm_out, (void*)&l16, (void*)&c_out, (void*)&h_out};
    hipLaunchCooperativeKernel((void*)lstm_phase2, dim3(256), dim3(512), args, 0, stream);
  }

  // phase 3: logits = lstm_out @ W_out + b_out
  gemm_f16<float><<<dim3(2, 512), 256, 0, stream>>>(l16, wot, b_out, logits, 65536, 256, 1024);
}

// Round 2
// 2378.851 us; speedup vs baseline: 18.0374x; 18.0374x over previous
//
#include <hip/hip_runtime.h>

// ---------------------------------------------------------------------------
// LSTM (B=128, T=512, D=512, H=1024, O=256), forget bias 1.0
//   prep:    f16 conversions/transposes/fragment-packing of weights
//   phase1:  xw = X @ W_x + b  (f16 MFMA GEMM, 65536x512x4096) -> ws
//   phase2:  persistent cooperative kernel, 512 sequential steps.
//            8 teams x 16 batch rows; 32 blocks/team each owning 32 hidden
//            units (128 gate cols). W_h fragments live in VGPRs. h exchanged
//            through coherent (sc0 sc1) stores/loads at the Infinity Cache +
//            per-block generation flags — NO threadfence / L2 wb-inv.
//   phase3:  logits = lstm_out @ W_out + b_out (f16 MFMA GEMM)
// ---------------------------------------------------------------------------

typedef _Float16 f16;
typedef _Float16 half8 __attribute__((ext_vector_type(8)));
typedef float floatx4 __attribute__((ext_vector_type(4)));

#define AS1 __attribute__((address_space(1)))
#define AS3 __attribute__((address_space(3)))

__device__ __forceinline__ void gload_lds16(const void* g, void* l) {
  __builtin_amdgcn_global_load_lds((const AS1 void*)g, (AS3 void*)l, 16, 0, 0);
}
// coherent (device-scope) variant: aux = SC0|SC1 = 1|16
__device__ __forceinline__ void gload_lds16_coh(const void* g, void* l) {
  __builtin_amdgcn_global_load_lds((const AS1 void*)g, (AS3 void*)l, 16, 0, 17);
}

__device__ __forceinline__ int load_flag_coh(const int* p) {
  int v;
  asm volatile("global_load_dword %0, %1, off sc0 sc1\n\ts_waitcnt vmcnt(0)"
               : "=v"(v) : "v"(p) : "memory");
  return v;
}
__device__ __forceinline__ void store_flag_coh(int* p, int v) {
  asm volatile("global_store_dword %0, %1, off sc0 sc1" :: "v"(p), "v"(v) : "memory");
}
__device__ __forceinline__ void store_h_coh(f16* p, f16 v) {
  unsigned int uv = (unsigned int)__builtin_bit_cast(unsigned short, v);
  asm volatile("global_store_short %0, %1, off sc0 sc1" :: "v"(p), "v"(uv) : "memory");
}

__device__ __forceinline__ float sigm(float x) { return 1.f / (1.f + __expf(-x)); }
__device__ __forceinline__ float tanh_fast(float x) {
  float ax = fabsf(x);
  float e = __expf(2.f * ax);          // overflows to +inf for big |x| -> t=1 exactly
  float t = 1.f - 2.f / (e + 1.f);
  return copysignf(t, x);
}

// ---------------- workspace layout ----------------
static constexpr size_t XW_OFF  = 0;
static constexpr size_t XW_BY   = (size_t)65536 * 4096 * 2;        // 536870912
static constexpr size_t L16_OFF = XW_OFF + XW_BY;                  // lstm_out f16 (aliases in16)
static constexpr size_t L16_BY  = (size_t)65536 * 1024 * 2;        // 134217728
static constexpr size_t IN16_OFF = L16_OFF;                        // inputs f16 (phase1 only)
static constexpr size_t WXT_OFF = L16_OFF + L16_BY;
static constexpr size_t WXT_BY  = (size_t)4096 * 512 * 2;
static constexpr size_t WOT_OFF = WXT_OFF + WXT_BY;
static constexpr size_t WOT_BY  = (size_t)256 * 1024 * 2;
static constexpr size_t WPK_OFF = WOT_OFF + WOT_BY;
static constexpr size_t WPK_BY  = (size_t)524288 * 8 * 2;          // W_h frag-packed
static constexpr size_t TH_OFF  = WPK_OFF + WPK_BY;
static constexpr size_t TH_BY   = (size_t)2 * 128 * 1024 * 2;      // h ping-pong
static constexpr size_t FLG_OFF = TH_OFF + TH_BY;
static constexpr size_t FLG_BY  = (size_t)8 * 32 * 4;              // gen flags[team][block]
static constexpr size_t WS_NEED = FLG_OFF + FLG_BY;

// ---------------- prep kernels ----------------
__global__ __launch_bounds__(256) void conv_f32_to_f16(const float* __restrict__ in,
                                                       f16* __restrict__ out) {
  size_t i = (size_t)blockIdx.x * 256 + threadIdx.x;
  const float4* in4 = (const float4*)in;
  float4 a = in4[i * 2], b = in4[i * 2 + 1];
  half8 v = {(f16)a.x, (f16)a.y, (f16)a.z, (f16)a.w,
             (f16)b.x, (f16)b.y, (f16)b.z, (f16)b.w};
  *(half8*)(out + i * 8) = v;
}

// out[c][r] = (f16)in[r][c]; grid = (C/64, R/64)
__global__ __launch_bounds__(256) void transpose_f32_to_f16(const float* __restrict__ in,
                                                            f16* __restrict__ out,
                                                            int R, int C) {
  __shared__ float tile[64][65];
  int tx = threadIdx.x & 63, ty = threadIdx.x >> 6;
  int c0 = blockIdx.x * 64, r0 = blockIdx.y * 64;
#pragma unroll
  for (int q = 0; q < 16; ++q) {
    int r = q * 4 + ty;
    tile[r][tx] = in[(size_t)(r0 + r) * C + c0 + tx];
  }
  __syncthreads();
#pragma unroll
  for (int q = 0; q < 16; ++q) {
    int oc = q * 4 + ty;
    out[(size_t)(c0 + oc) * R + r0 + tx] = (f16)tile[tx][oc];
  }
}

// Pack W_h (rows 512..1535 of W_lstm) into per-(colblock,wave,ni,ks,lane) f16x8
// fragments matching the phase-2 MFMA B-operand layout (n=lane&15, k=(lane>>4)*8+e).
__global__ __launch_bounds__(256) void pack_wh(const float* __restrict__ W,
                                               f16* __restrict__ wpack) {
  int s = blockIdx.x * 256 + threadIdx.x;   // 0 .. 524287
  int lane = s & 63;
  int ks = (s >> 6) & 7;
  int ni = (s >> 9) & 3;
  int w  = (s >> 11) & 7;
  int cb = s >> 14;                          // 0..31
  int nh = w & 1, ksl = w >> 1;
  int c = nh * 64 + ni * 16 + (lane & 15);   // block-local col 0..127
  int g = c >> 5, ul = c & 31;
  int ncol = g * 1024 + cb * 32 + ul;        // global gate col
  int kb = ksl * 256 + ks * 32 + (lane >> 4) * 8;
  half8 v;
#pragma unroll
  for (int e = 0; e < 8; ++e)
    v[e] = (f16)W[(size_t)(512 + kb + e) * 4096 + ncol];
  ((half8*)wpack)[s] = v;
}

// ---------------- generic f16 MFMA GEMM: C = A[MxK] * Bt[NxK]^T + bias ----------------
template <typename OT>
__global__ __launch_bounds__(256) void gemm_f16(const f16* __restrict__ A,
                                                const f16* __restrict__ Bt,
                                                const float* __restrict__ bias,
                                                OT* __restrict__ C,
                                                int M, int N, int K) {
  __shared__ __align__(16) char smem[32768];   // As 16K | Bs 16K
  const int tid = threadIdx.x;
  const int n0 = blockIdx.x * 128, m0 = blockIdx.y * 128;
  const int l = tid & 63, w = tid >> 6;
  const int wr = w >> 1, wc = w & 1;
  const int r16 = l & 15, hi = l >> 4;
  floatx4 acc[4][4];
#pragma unroll
  for (int a = 0; a < 4; ++a)
#pragma unroll
    for (int b = 0; b < 4; ++b) acc[a][b] = (floatx4){0.f, 0.f, 0.f, 0.f};

  const int nk = K >> 6;
  for (int kk = 0; kk < nk; ++kk) {
    __syncthreads();
#pragma unroll
    for (int q = 0; q < 4; ++q) {
      int c = q * 256 + tid;
      int row = c >> 3, g8 = c & 7;
      gload_lds16(A + (size_t)(m0 + row) * K + kk * 64 + g8 * 8, smem + c * 16);
    }
#pragma unroll
    for (int q = 0; q < 4; ++q) {
      int c = q * 256 + tid;
      int row = c >> 3, g8 = c & 7;
      gload_lds16(Bt + (size_t)(n0 + row) * K + kk * 64 + g8 * 8, smem + 16384 + c * 16);
    }
    __syncthreads();
#pragma unroll
    for (int ks = 0; ks < 2; ++ks) {
      half8 af[4], bf[4];
#pragma unroll
      for (int mi = 0; mi < 4; ++mi)
        af[mi] = *(const half8*)(smem + ((wr * 64 + mi * 16 + r16) * 64 + ks * 32 + hi * 8) * 2);
#pragma unroll
      for (int ni = 0; ni < 4; ++ni)
        bf[ni] = *(const half8*)(smem + 16384 +
                                 ((wc * 64 + ni * 16 + r16) * 64 + ks * 32 + hi * 8) * 2);
#pragma unroll
      for (int mi = 0; mi < 4; ++mi)
#pragma unroll
        for (int ni = 0; ni < 4; ++ni)
          acc[mi][ni] = __builtin_amdgcn_mfma_f32_16x16x32_f16(af[mi], bf[ni], acc[mi][ni], 0, 0, 0);
    }
  }
#pragma unroll
  for (int ni = 0; ni < 4; ++ni) {
    int col = n0 + wc * 64 + ni * 16 + r16;
    float bv = bias[col];
#pragma unroll
    for (int mi = 0; mi < 4; ++mi)
#pragma unroll
      for (int rr = 0; rr < 4; ++rr) {
        int row = m0 + wr * 64 + mi * 16 + hi * 4 + rr;
        C[(size_t)row * N + col] = (OT)(acc[mi][ni][rr] + bv);
      }
  }
}

// ---------------- phase 2: persistent recurrent kernel ----------------
// grid 256 blocks x 512 threads. block bk: team = bk>>5 (16 batch rows),
// colblock cb = bk&31 (hidden units u0..u0+31 -> gate cols {g*1024+u0+ul}).
// wave w: ksl = w>>1 (K slice of 256), nh = w&1 (64-col half).
__global__ __launch_bounds__(512, 2)
void lstm_phase2(const f16* __restrict__ wpack, const f16* __restrict__ xw,
                 const float* __restrict__ c_in, const float* __restrict__ h_in,
                 const int* __restrict__ seq_lens,
                 f16* teamh, int* flags,
                 float* __restrict__ lstm_out, f16* __restrict__ lstm16,
                 float* __restrict__ c_out, float* __restrict__ h_out) {
  __shared__ __align__(16) char smem[65536];   // h_lds 32K (swizzled) | red 32K
  const int tid = threadIdx.x;
  const int bk = blockIdx.x;
  const int team = bk >> 5, cb = bk & 31;
  const int b0 = team * 16;
  const int u0 = cb * 32;
  const int l = tid & 63, w = tid >> 6;
  const int nh = w & 1, ksl = w >> 1;
  const int r16 = l & 15, hi = l >> 4;

  // persistent W_h fragments: 32 x f16x8 = 128 VGPRs
  half8 wf[4][8];
  {
    const half8* wp = (const half8*)wpack;
    size_t base = (size_t)((cb * 8 + w) * 4) * 8 * 64;
#pragma unroll
    for (int ni = 0; ni < 4; ++ni)
#pragma unroll
      for (int ks = 0; ks < 8; ++ks)
        wf[ni][ks] = wp[base + (size_t)(ni * 8 + ks) * 64 + l];
  }

  const int bb = tid >> 5, ul = tid & 31;     // consumer identity: batch row, unit
  const int bglob = b0 + bb;
  const int nunit = u0 + ul;
  float creg = c_in[bglob * 1024 + nunit];
  float hreg = h_in[bglob * 1024 + nunit];
  const int slen = seq_lens[bglob];

  float* red = (float*)(smem + 32768);
  int* myflags = flags + team * 32;

#pragma unroll 1
  for (int t = 0; t < 512; ++t) {
    // prefetch this step's x-projection (independent of the flag, L2-cached)
    f16 xwv0, xwv1, xwv2, xwv3;
    {
      const f16* xp = xw + ((size_t)bglob * 512 + t) * 4096 + nunit;
      xwv0 = xp[0]; xwv1 = xp[1024]; xwv2 = xp[2048]; xwv3 = xp[3072];
    }

    if (t > 0) {
      // wave 0: 32 lanes poll the 32 per-block generation flags in parallel
      if (tid < 64) {
        const int* fp = myflags + (tid & 31);
        while (true) {
          int g = load_flag_coh(fp);
          if (__all((tid >= 32) | (g >= t))) break;
          __builtin_amdgcn_s_sleep(1);
        }
      }
      __syncthreads();
      const char* hb = (const char*)teamh + (size_t)(t & 1) * (128 * 1024 * 2);
#pragma unroll
      for (int q = 0; q < 4; ++q) {
        int G = q * 512 + tid;          // 16B granule id; 128 granules per h row
        int r = G >> 7, p = G & 127;
        int dg = p ^ (r & 7);           // inverse-swizzled source (linear LDS dest)
        gload_lds16_coh(hb + ((size_t)(b0 + r) * 1024 + dg * 8) * 2, smem + G * 16);
      }
    } else {
      // first step: stage h_in (fp32 -> f16) with the same swizzle
#pragma unroll
      for (int q = 0; q < 4; ++q) {
        int G = q * 512 + tid;
        int r = G >> 7, p = G & 127;
        int dg = p ^ (r & 7);
        const float* s = h_in + (size_t)(b0 + r) * 1024 + dg * 8;
        half8 v;
#pragma unroll
        for (int e = 0; e < 8; ++e) v[e] = (f16)s[e];
        *(half8*)(smem + G * 16) = v;
      }
    }
    __syncthreads();

    // MFMA: gates_partial[16 x 64cols] over K slice of 256
    floatx4 acc0 = {0.f, 0.f, 0.f, 0.f}, acc1 = acc0, acc2 = acc0, acc3 = acc0;
#pragma unroll
    for (int ks = 0; ks < 8; ++ks) {
      int gran = ksl * 32 + ks * 4 + hi;
      int phys = gran ^ (r16 & 7);      // swizzled read -> conflict-free b128
      half8 a = *(const half8*)(smem + r16 * 2048 + phys * 16);
      acc0 = __builtin_amdgcn_mfma_f32_16x16x32_f16(a, wf[0][ks], acc0, 0, 0, 0);
      acc1 = __builtin_amdgcn_mfma_f32_16x16x32_f16(a, wf[1][ks], acc1, 0, 0, 0);
      acc2 = __builtin_amdgcn_mfma_f32_16x16x32_f16(a, wf[2][ks], acc2, 0, 0, 0);
      acc3 = __builtin_amdgcn_mfma_f32_16x16x32_f16(a, wf[3][ks], acc3, 0, 0, 0);
    }
    {
      int cbase = nh * 64 + r16;
      int rbase = ksl * 16 + hi * 4;
#pragma unroll
      for (int rr = 0; rr < 4; ++rr) {
        float* rp = red + (size_t)(rbase + rr) * 128 + cbase;
        rp[0] = acc0[rr]; rp[16] = acc1[rr]; rp[32] = acc2[rr]; rp[48] = acc3[rr];
      }
    }
    __syncthreads();

    // reduce 4 K-slices + x-projection, then gate nonlinearities
    float g0 = (float)xwv0, g1 = (float)xwv1, g2 = (float)xwv2, g3 = (float)xwv3;
#pragma unroll
    for (int p = 0; p < 4; ++p) {
      const float* rp = red + ((size_t)p * 16 + bb) * 128 + ul;
      g0 += rp[0]; g1 += rp[32]; g2 += rp[64]; g3 += rp[96];
    }
    float nc = creg * sigm(g2 + 1.f) + sigm(g0) * tanh_fast(g1);   // i,j,f,o order
    float nhv = tanh_fast(nc) * sigm(g3);
    bool valid = t < slen;
    if (valid) { creg = nc; hreg = nhv; }
    float outv = valid ? nhv : 0.f;
    size_t orow = ((size_t)bglob * 512 + t) * 1024 + nunit;

    // coherent h store first (the only store the flag protects)
    store_h_coh(teamh + (size_t)((t + 1) & 1) * 131072 + bglob * 1024 + nunit, (f16)hreg);
    // bulk outputs: normal cached stores, written back lazily
    lstm_out[orow] = outv;
    lstm16[orow] = (f16)outv;

    asm volatile("s_waitcnt vmcnt(0)" ::: "memory");  // per-wave: h store committed at IF$
    __syncthreads();                                   // all waves committed
    if (tid == 0) store_flag_coh(myflags + cb, t + 1); // publish generation
  }

  c_out[bglob * 1024 + nunit] = creg;
  h_out[bglob * 1024 + nunit] = hreg;
}

// ---------------- host ----------------
extern "C" void kernel_launch(void* const* d_in, const int* in_sizes, int n_in,
                              void* d_out, int out_size, void* d_ws, size_t ws_size,
                              hipStream_t stream) {
  const float* inputs  = (const float*)d_in[0];
  const float* c_in    = (const float*)d_in[1];
  const float* h_in    = (const float*)d_in[2];
  const float* W_lstm  = (const float*)d_in[3];
  const float* b_lstm  = (const float*)d_in[4];
  const float* W_out   = (const float*)d_in[5];
  const float* b_out   = (const float*)d_in[6];
  const int*   seq_lens= (const int*)d_in[7];

  float* logits  = (float*)d_out;
  float* lstm_out= logits + (size_t)65536 * 256;
  float* c_out   = lstm_out + (size_t)65536 * 1024;
  float* h_out   = c_out + (size_t)128 * 1024;

  if (ws_size < WS_NEED) return;   // fail visibly (poison stays) rather than corrupt

  char* ws = (char*)d_ws;
  f16* xw    = (f16*)(ws + XW_OFF);
  f16* in16  = (f16*)(ws + IN16_OFF);
  f16* l16   = (f16*)(ws + L16_OFF);
  f16* wxt   = (f16*)(ws + WXT_OFF);
  f16* wot   = (f16*)(ws + WOT_OFF);
  f16* wpk   = (f16*)(ws + WPK_OFF);
  f16* teamh = (f16*)(ws + TH_OFF);
  int* flags = (int*)(ws + FLG_OFF);

  hipMemsetAsync(flags, 0, FLG_BY, stream);
  conv_f32_to_f16<<<16384, 256, 0, stream>>>(inputs, in16);
  transpose_f32_to_f16<<<dim3(64, 8), 256, 0, stream>>>(W_lstm, wxt, 512, 4096);
  transpose_f32_to_f16<<<dim3(4, 16), 256, 0, stream>>>(W_out, wot, 1024, 256);
  pack_wh<<<2048, 256, 0, stream>>>(W_lstm, wpk);

  // phase 1: xw = X @ W_x + b_lstm
  gemm_f16<f16><<<dim3(32, 512), 256, 0, stream>>>(in16, wxt, b_lstm, xw, 65536, 4096, 512);

  // phase 2: persistent recurrence (cooperative => co-residency guaranteed)
  {
    const f16* wpk_c = wpk;
    const f16* xw_c  = xw;
    void* args[] = {(void*)&wpk_c, (void*)&xw_c, (void*)&c_in, (void*)&h_in,
                    (void*)&seq_lens, (void*)&teamh, (void*)&flags,
                    (void*)&lstm_out, (void*)&l16, (void*)&c_out, (void*)&h_out};
    hipLaunchCooperativeKernel((void*)lstm_phase2, dim3(256), dim3(512), args, 0, stream);
  }

  // phase 3: logits = lstm_out @ W_out + b_out
  gemm_f16<float><<<dim3(2, 512), 256, 0, stream>>>(l16, wot, b_out, logits, 65536, 256, 1024);
}